// Round 9
// baseline (44.890 us; speedup 1.0000x reference)
//
#include <hip/hip_runtime.h>

// VAR flex-attention, MI355X gfx950. Mask == "q attends to keys [0, block_end(q))".
// R9: 32q-per-wave LDS-BW fix WITHOUT the R8 occupancy loss. 256-thread /
// 4-wave blocks, QBLK=128, depth-2 double-buffered LDS (32KB -> 4 blocks/CU,
// 16 waves/CU at VGPR<=128). One K/V ds_read feeds two q-halves' MFMAs ->
// LDS read traffic per q halves vs R7. Schedule = R2/R6 proven: gload_lds 16B,
// WAITV(4) -> barrier -> compute -> barrier -> issue(kt+2). Body = R5 proven:
// fixed-max exp2 softmax, cvt_pk packing, gathered pre-swizzled V, setprio.

typedef float  f32x4 __attribute__((ext_vector_type(4)));
typedef short  s16x8 __attribute__((ext_vector_type(8)));
typedef short  s16x4 __attribute__((ext_vector_type(4)));
typedef unsigned int u32;
typedef u32    u32x4 __attribute__((ext_vector_type(4)));

#define L_TOK 680
#define LPAD  704
#define DHEAD 64
#define NBH   128
#define NTILE 11
#define SCALE_LOG2 0.18033688011112042f   // (1/8) * log2(e)

#define WAITV(n) asm volatile("s_waitcnt vmcnt(" #n ")" ::: "memory")

__device__ __forceinline__ int kv_len(int q) {
  return q < 1 ? 1 : q < 5 ? 5 : q < 14 ? 14 : q < 30 ? 30 : q < 55 ? 55
       : q < 91 ? 91 : q < 155 ? 155 : q < 255 ? 255 : q < 424 ? 424 : L_TOK;
}

__device__ __forceinline__ short f2bf(float x) {
  unsigned u = __float_as_uint(x);
  return (short)((u + 0x7FFFu + ((u >> 16) & 1u)) >> 16);
}

__device__ __forceinline__ s16x8 cvt8(f32x4 a, f32x4 b, float sc) {
  s16x8 f;
  f[0] = f2bf(a[0] * sc); f[1] = f2bf(a[1] * sc);
  f[2] = f2bf(a[2] * sc); f[3] = f2bf(a[3] * sc);
  f[4] = f2bf(b[0] * sc); f[5] = f2bf(b[1] * sc);
  f[6] = f2bf(b[2] * sc); f[7] = f2bf(b[3] * sc);
  return f;
}

__device__ __forceinline__ float exp2f_raw(float x) {
  float r; asm("v_exp_f32 %0, %1" : "=v"(r) : "v"(x)); return r;
}
__device__ __forceinline__ u32 cvtpk(float lo, float hi) {
  u32 r; asm("v_cvt_pk_bf16_f32 %0, %1, %2" : "=v"(r) : "v"(lo), "v"(hi)); return r;
}

__device__ __forceinline__ void gload16(const void* g, void* l) {
  __builtin_amdgcn_global_load_lds(
      (const __attribute__((address_space(1))) u32*)g,
      (__attribute__((address_space(3))) u32*)l, 16, 0, 0);
}

// ---- fused prepass (identical to R4..R8, proven) ----------------------------
__global__ __launch_bounds__(256) void prep_kv(
    const float* __restrict__ Kg, const float* __restrict__ Vg,
    short* __restrict__ Ks, short* __restrict__ Vt2)
{
  int b = blockIdx.x, tid = threadIdx.x;
  if (b < 2816) {
    int g = b * 256 + tid;
    int bh = g / (LPAD * 8);
    int rem = g - bh * (LPAD * 8);
    int r = rem >> 3, c = rem & 7;
    s16x8 o = (s16x8)0;
    if (r < L_TOK) {
      const float* src = Kg + ((size_t)(bh * L_TOK + r)) * DHEAD + c * 8;
      f32x4 a = *(const f32x4*)src;
      f32x4 bb = *(const f32x4*)(src + 4);
      o = cvt8(a, bb, 1.0f);
    }
    int cp = c ^ (r & 7);
    *(s16x8*)(Ks + ((size_t)(bh * LPAD + r)) * DHEAD + cp * 8) = o;
  } else {
    int bid = b - 2816;                       // bh*11 + t
    int bh = bid / NTILE, t = bid - bh * NTILE;
    int lg = tid & 3, l15 = (tid >> 2) & 15, dt = tid >> 6;
    int d = dt * 16 + l15;
    const float* vsrc = Vg + (size_t)bh * L_TOK * DHEAD + d;
    short* rowbase = Vt2 + ((size_t)(bh * NTILE + t)) * 4096 + d * 64;
    #pragma unroll
    for (int f = 0; f < 2; ++f) {
      short u[8];
      #pragma unroll
      for (int i = 0; i < 4; ++i) {
        int kv = t * 64 + f * 32 + lg * 4 + i;
        u[i]     = (kv < L_TOK)      ? f2bf(vsrc[(size_t)kv * DHEAD])        : (short)0;
        u[4 + i] = (kv + 16 < L_TOK) ? f2bf(vsrc[(size_t)(kv + 16) * DHEAD]) : (short)0;
      }
      int pos = (2 * lg + f) ^ (l15 & 7);
      *(s16x8*)(rowbase + pos * 8) = *(const s16x8*)u;
    }
  }
}

// ---- main kernel: 4 waves x 32 q = 128q per block, 64-kv tiles, depth-2 -----
__global__ __launch_bounds__(256, 4) void var_attn9(
    const float* __restrict__ Qg, const short* __restrict__ Ks,
    const short* __restrict__ Vt2, float* __restrict__ Og)
{
  const int tid  = threadIdx.x;
  const int lane = tid & 63, wave = tid >> 6;
  const int l15  = lane & 15, lg = lane >> 4;

  // dispatch: bid&7 -> XCD-stable bh-low (L2 reuse); long q-tiles first
  int bid  = blockIdx.x;                      // 0..767
  int bhlo = bid & 7;
  int t_   = bid >> 3;                        // 0..95
  int qbi  = t_ >> 4;                         // 0..5
  int bhhi = t_ & 15;
  int qb2  = (qbi < 3) ? (qbi + 3) : (5 - qbi);   // 3,4,5,2,1,0 (nt 11,11,11,7,4,3)
  int bh   = bhhi * 8 + bhlo;
  int qblk = qb2 * 128;

  __shared__ short kbuf[2][64 * DHEAD];       // 2 x 8KB
  __shared__ short vbuf[2][64 * DHEAD];       // 2 x 8KB (gathered V fragments)

  const int qw        = qblk + wave * 32;     // wave's first query (32-q span)
  const int q0c       = min(qw + l15,      L_TOK - 1);
  const int q1c       = min(qw + 16 + l15, L_TOK - 1);
  const int kvlen0    = kv_len(q0c);
  const int kvlen1    = kv_len(q1c);
  const int kvmin_w   = kv_len(min(qw, L_TOK - 1));
  const int kv_need_w = kv_len(min(qw + 31, L_TOK - 1));
  const int nkv       = kv_len(min(qblk + 127, L_TOK - 1));
  const int nt        = (nkv + 63) >> 6;      // 3,4,7,11,11,11 -> >= 3

  // Q fragments for both q-halves, pre-scaled into log2 domain
  s16x8 qf0[2], qf1[2];
  {
    const float* qp0 = Qg + ((size_t)(bh * L_TOK + q0c)) * DHEAD + lg * 8;
    const float* qp1 = Qg + ((size_t)(bh * L_TOK + q1c)) * DHEAD + lg * 8;
    #pragma unroll
    for (int ks = 0; ks < 2; ++ks) {
      f32x4 a0 = *(const f32x4*)(qp0 + ks * 32);
      f32x4 b0 = *(const f32x4*)(qp0 + ks * 32 + 4);
      qf0[ks] = cvt8(a0, b0, SCALE_LOG2);
      f32x4 a1 = *(const f32x4*)(qp1 + ks * 32);
      f32x4 b1 = *(const f32x4*)(qp1 + ks * 32 + 4);
      qf1[ks] = cvt8(a1, b1, SCALE_LOG2);
    }
  }

  const short* ksb = Ks + (size_t)bh * LPAD * DHEAD;
  const short* vtb = Vt2 + (size_t)bh * NTILE * 4096;

  auto issue = [&](int kt, int buf) {         // 2 K + 2 V 16B loads per lane
    #pragma unroll
    for (int c = 0; c < 2; ++c) {
      int off = c * 4096 + tid * 16;
      gload16((const char*)(ksb + kt * 4096) + off, (char*)&kbuf[buf][0] + off);
    }
    #pragma unroll
    for (int c = 0; c < 2; ++c) {
      int off = c * 4096 + tid * 16;
      gload16((const char*)(vtb + (size_t)kt * 4096) + off, (char*)&vbuf[buf][0] + off);
    }
  };

  issue(0, 0);
  issue(1, 1);

  // hoisted loop-invariant LDS byte offsets
  const int swz   = l15 & 7;
  const int koff0 = l15 * 128 + ((lg    ) ^ swz) * 16;
  const int koff1 = l15 * 128 + ((lg + 4) ^ swz) * 16;
  const int voff0 = l15 * 128 + ((2 * lg    ) ^ swz) * 16;
  const int voff1 = l15 * 128 + ((2 * lg + 1) ^ swz) * 16;

  f32x4 o0[4] = {}, o1[4] = {};
  float l0 = 0.0f, l1 = 0.0f;

  for (int kt = 0; kt < nt; ++kt) {
    if (kt < nt - 1) { WAITV(4); } else { WAITV(0); }
    __builtin_amdgcn_s_barrier();

    const int kv0 = kt * 64;
    if (kv0 < kv_need_w) {
      const char* kb = (const char*)&kbuf[kt & 1][0];
      const char* vb = (const char*)&vbuf[kt & 1][0];

      // QK^T (swapped): one K read feeds both q-halves
      f32x4 s0a[4], s1a[4];
      #pragma unroll
      for (int t16 = 0; t16 < 4; ++t16) { s0a[t16] = (f32x4)0; s1a[t16] = (f32x4)0; }
      __builtin_amdgcn_s_setprio(1);
      #pragma unroll
      for (int t16 = 0; t16 < 4; ++t16) {
        s16x8 kfa = *(const s16x8*)(kb + t16 * 2048 + koff0);
        s16x8 kfb = *(const s16x8*)(kb + t16 * 2048 + koff1);
        s0a[t16] = __builtin_amdgcn_mfma_f32_16x16x32_bf16(kfa, qf0[0], s0a[t16], 0, 0, 0);
        s0a[t16] = __builtin_amdgcn_mfma_f32_16x16x32_bf16(kfb, qf0[1], s0a[t16], 0, 0, 0);
        s1a[t16] = __builtin_amdgcn_mfma_f32_16x16x32_bf16(kfa, qf1[0], s1a[t16], 0, 0, 0);
        s1a[t16] = __builtin_amdgcn_mfma_f32_16x16x32_bf16(kfb, qf1[1], s1a[t16], 0, 0, 0);
      }
      __builtin_amdgcn_s_setprio(0);

      // mask + fixed-max softmax (p = exp2(s), in place), both q-halves
      float p0[16], p1[16];
      if (kv0 + 64 <= kvmin_w) {
        #pragma unroll
        for (int t16 = 0; t16 < 4; ++t16)
          #pragma unroll
          for (int r = 0; r < 4; ++r) {
            p0[t16 * 4 + r] = exp2f_raw(s0a[t16][r]);
            p1[t16 * 4 + r] = exp2f_raw(s1a[t16][r]);
          }
      } else {
        #pragma unroll
        for (int t16 = 0; t16 < 4; ++t16)
          #pragma unroll
          for (int r = 0; r < 4; ++r) {
            int key = kv0 + t16 * 16 + lg * 4 + r;
            p0[t16 * 4 + r] = (key < kvlen0) ? exp2f_raw(s0a[t16][r]) : 0.0f;
            p1[t16 * 4 + r] = (key < kvlen1) ? exp2f_raw(s1a[t16][r]) : 0.0f;
          }
      }
      {
        float a0 = (p0[0] + p0[1]) + (p0[2] + p0[3]);
        float a1 = (p0[4] + p0[5]) + (p0[6] + p0[7]);
        float a2 = (p0[8] + p0[9]) + (p0[10] + p0[11]);
        float a3 = (p0[12] + p0[13]) + (p0[14] + p0[15]);
        l0 += (a0 + a1) + (a2 + a3);
        float b0 = (p1[0] + p1[1]) + (p1[2] + p1[3]);
        float b1 = (p1[4] + p1[5]) + (p1[6] + p1[7]);
        float b2 = (p1[8] + p1[9]) + (p1[10] + p1[11]);
        float b3 = (p1[12] + p1[13]) + (p1[14] + p1[15]);
        l1 += (b0 + b1) + (b2 + b3);
      }

      // pack P to bf16 fragments (pf{qh}{f}: f=0 -> kv 0..31, f=1 -> 32..63)
      u32x4 w00, w01, w10, w11;
      w00[0] = cvtpk(p0[0],  p0[1]);  w00[1] = cvtpk(p0[2],  p0[3]);
      w00[2] = cvtpk(p0[4],  p0[5]);  w00[3] = cvtpk(p0[6],  p0[7]);
      w01[0] = cvtpk(p0[8],  p0[9]);  w01[1] = cvtpk(p0[10], p0[11]);
      w01[2] = cvtpk(p0[12], p0[13]); w01[3] = cvtpk(p0[14], p0[15]);
      w10[0] = cvtpk(p1[0],  p1[1]);  w10[1] = cvtpk(p1[2],  p1[3]);
      w10[2] = cvtpk(p1[4],  p1[5]);  w10[3] = cvtpk(p1[6],  p1[7]);
      w11[0] = cvtpk(p1[8],  p1[9]);  w11[1] = cvtpk(p1[10], p1[11]);
      w11[2] = cvtpk(p1[12], p1[13]); w11[3] = cvtpk(p1[14], p1[15]);
      s16x8 pf00 = __builtin_bit_cast(s16x8, w00);
      s16x8 pf01 = __builtin_bit_cast(s16x8, w01);
      s16x8 pf10 = __builtin_bit_cast(s16x8, w10);
      s16x8 pf11 = __builtin_bit_cast(s16x8, w11);

      // PV: one V read feeds both q-halves
      __builtin_amdgcn_s_setprio(1);
      #pragma unroll
      for (int dt = 0; dt < 4; ++dt) {
        s16x8 vf0 = *(const s16x8*)(vb + dt * 2048 + voff0);
        s16x8 vf1 = *(const s16x8*)(vb + dt * 2048 + voff1);
        o0[dt] = __builtin_amdgcn_mfma_f32_16x16x32_bf16(pf00, vf0, o0[dt], 0, 0, 0);
        o0[dt] = __builtin_amdgcn_mfma_f32_16x16x32_bf16(pf01, vf1, o0[dt], 0, 0, 0);
        o1[dt] = __builtin_amdgcn_mfma_f32_16x16x32_bf16(pf10, vf0, o1[dt], 0, 0, 0);
        o1[dt] = __builtin_amdgcn_mfma_f32_16x16x32_bf16(pf11, vf1, o1[dt], 0, 0, 0);
      }
      __builtin_amdgcn_s_setprio(0);
    }
    __builtin_amdgcn_s_barrier();
    if (kt + 2 < nt) issue(kt + 2, kt & 1);   // just-consumed buffer
  }

  // epilogue: reduce l across the 4 replica lane-groups, normalize, store
  l0 += __shfl_xor(l0, 16); l0 += __shfl_xor(l0, 32);
  l1 += __shfl_xor(l1, 16); l1 += __shfl_xor(l1, 32);
  float li0 = 1.0f / l0, li1 = 1.0f / l1;
  float s0q[4], s1q[4];
  #pragma unroll
  for (int r = 0; r < 4; ++r) {
    s0q[r] = __shfl(li0, lg * 4 + r);
    s1q[r] = __shfl(li1, lg * 4 + r);
  }
  #pragma unroll
  for (int r = 0; r < 4; ++r) {
    int qo0 = qw + lg * 4 + r;
    if (qo0 < L_TOK) {
      float* dst = Og + ((size_t)(bh * L_TOK + qo0)) * DHEAD + l15;
      #pragma unroll
      for (int dt = 0; dt < 4; ++dt) dst[dt * 16] = o0[dt][r] * s0q[r];
    }
    int qo1 = qw + 16 + lg * 4 + r;
    if (qo1 < L_TOK) {
      float* dst = Og + ((size_t)(bh * L_TOK + qo1)) * DHEAD + l15;
      #pragma unroll
      for (int dt = 0; dt < 4; ++dt) dst[dt * 16] = o1[dt][r] * s1q[r];
    }
  }
}

// ---------------- R1 fallback kernel (f32 direct, no workspace) --------------
#define QBLK1  64
#define KVBLK1 32
#define VTS    36
__global__ __launch_bounds__(256, 2) void var_attn(
    const float* __restrict__ Qg, const float* __restrict__ Kg,
    const float* __restrict__ Vg, float* __restrict__ Og)
{
  const int tid  = threadIdx.x;
  const int bh   = blockIdx.y;
  const int qblk = blockIdx.x * QBLK1;
  const int wave = tid >> 6;
  const int lane = tid & 63;
  const int l15  = lane & 15;
  const int lg   = lane >> 4;

  __shared__ short kbuf[KVBLK1 * DHEAD];
  __shared__ short vtbuf[DHEAD * VTS];

  const int qw   = qblk + wave * 16;
  const int qc   = min(qw + l15, L_TOK - 1);
  const int my_kvlen  = kv_len(qc);
  const int kv_need_w = kv_len(min(qw + 15, L_TOK - 1));
  const int nkv       = kv_len(min(qblk + QBLK1 - 1, L_TOK - 1));

  s16x8 qfrag[2];
  {
    const float* qptr = Qg + ((size_t)(bh * L_TOK + qc)) * DHEAD + lg * 8;
    #pragma unroll
    for (int ks = 0; ks < 2; ++ks) {
      f32x4 a = *(const f32x4*)(qptr + ks * 32);
      f32x4 b = *(const f32x4*)(qptr + ks * 32 + 4);
      qfrag[ks] = cvt8(a, b, 0.125f);
    }
  }

  f32x4 oacc[4] = {};
  float m_run = -1e30f, l_run = 0.0f;

  const int stage_r = tid >> 3;
  const int stage_c = (tid & 7) * 8;
  const float* kbase = Kg + (size_t)bh * L_TOK * DHEAD;
  const float* vbase = Vg + (size_t)bh * L_TOK * DHEAD;

  for (int kv0 = 0; kv0 < nkv; kv0 += KVBLK1) {
    {
      const int rsrc = min(kv0 + stage_r, L_TOK - 1);
      const float* ks_ = kbase + (size_t)rsrc * DHEAD + stage_c;
      f32x4 a = *(const f32x4*)ks_;
      f32x4 b = *(const f32x4*)(ks_ + 4);
      s16x8 kf = cvt8(a, b, 1.0f);
      int boff = (stage_r * 128 + stage_c * 2) ^ ((stage_r & 7) << 4);
      *(s16x8*)((char*)kbuf + boff) = kf;
      const float* vs_ = vbase + (size_t)rsrc * DHEAD + stage_c;
      f32x4 c = *(const f32x4*)vs_;
      f32x4 d = *(const f32x4*)(vs_ + 4);
      #pragma unroll
      for (int i = 0; i < 4; ++i) vtbuf[(stage_c + i) * VTS + stage_r] = f2bf(c[i]);
      #pragma unroll
      for (int i = 0; i < 4; ++i) vtbuf[(stage_c + 4 + i) * VTS + stage_r] = f2bf(d[i]);
    }
    __syncthreads();
    if (kv0 < kv_need_w) {
      f32x4 sacc[2] = {};
      #pragma unroll
      for (int t = 0; t < 2; ++t) {
        const int kr = t * 16 + l15;
        #pragma unroll
        for (int ks = 0; ks < 2; ++ks) {
          int boff = (kr * 128 + (lg * 8 + ks * 32) * 2) ^ ((kr & 7) << 4);
          s16x8 kf = *(const s16x8*)((char*)kbuf + boff);
          sacc[t] = __builtin_amdgcn_mfma_f32_16x16x32_bf16(kf, qfrag[ks], sacc[t], 0, 0, 0);
        }
      }
      float s[8];
      #pragma unroll
      for (int t = 0; t < 2; ++t)
        #pragma unroll
        for (int r = 0; r < 4; ++r) {
          int key = kv0 + t * 16 + lg * 4 + r;
          s[t * 4 + r] = (key < my_kvlen) ? sacc[t][r] : -1e30f;
        }
      float mt = s[0];
      #pragma unroll
      for (int i = 1; i < 8; ++i) mt = fmaxf(mt, s[i]);
      mt = fmaxf(mt, __shfl_xor(mt, 16));
      mt = fmaxf(mt, __shfl_xor(mt, 32));
      float m_new = fmaxf(m_run, mt);
      float sc = __expf(m_run - m_new);
      float psum = 0.0f;
      short pf[8];
      #pragma unroll
      for (int i = 0; i < 8; ++i) {
        float pp = __expf(s[i] - m_new);
        psum += pp;
        pf[i] = f2bf(pp);
      }
      psum += __shfl_xor(psum, 16);
      psum += __shfl_xor(psum, 32);
      l_run = l_run * sc + psum;
      m_run = m_new;
      float sc_q[4];
      #pragma unroll
      for (int r = 0; r < 4; ++r) sc_q[r] = __shfl(sc, lg * 4 + r);
      #pragma unroll
      for (int dt = 0; dt < 4; ++dt)
        #pragma unroll
        for (int r = 0; r < 4; ++r) oacc[dt][r] *= sc_q[r];
      s16x8 pfrag;
      #pragma unroll
      for (int i = 0; i < 8; ++i) pfrag[i] = pf[i];
      #pragma unroll
      for (int dt = 0; dt < 4; ++dt) {
        const short* row = vtbuf + (dt * 16 + l15) * VTS + lg * 4;
        s16x4 v0 = *(const s16x4*)row;
        s16x4 v1 = *(const s16x4*)(row + 16);
        s16x8 vf;
        vf[0] = v0[0]; vf[1] = v0[1]; vf[2] = v0[2]; vf[3] = v0[3];
        vf[4] = v1[0]; vf[5] = v1[1]; vf[6] = v1[2]; vf[7] = v1[3];
        oacc[dt] = __builtin_amdgcn_mfma_f32_16x16x32_bf16(pfrag, vf, oacc[dt], 0, 0, 0);
      }
    }
    __syncthreads();
  }

  float linv = 1.0f / l_run;
  float li_q[4];
  #pragma unroll
  for (int r = 0; r < 4; ++r) li_q[r] = __shfl(linv, lg * 4 + r);
  #pragma unroll
  for (int r = 0; r < 4; ++r) {
    int qo = qw + lg * 4 + r;
    if (qo < L_TOK) {
      float* dst = Og + ((size_t)(bh * L_TOK + qo)) * DHEAD + l15;
      #pragma unroll
      for (int dt = 0; dt < 4; ++dt) dst[dt * 16] = oacc[dt][r] * li_q[r];
    }
  }
}

extern "C" void kernel_launch(void* const* d_in, const int* in_sizes, int n_in,
                              void* d_out, int out_size, void* d_ws, size_t ws_size,
                              hipStream_t stream) {
  const float* q = (const float*)d_in[0];
  const float* k = (const float*)d_in[1];
  const float* v = (const float*)d_in[2];
  float* o = (float*)d_out;

  const size_t ksz  = (size_t)NBH * LPAD * DHEAD;     // shorts (= Vt2 size too)
  const size_t need = 2 * ksz * sizeof(short);        // 23.1 MB
  if (ws_size >= need) {
    short* Ks  = (short*)d_ws;
    short* Vt2 = Ks + ksz;
    prep_kv<<<4224, 256, 0, stream>>>(k, v, Ks, Vt2);
    var_attn9<<<768, 256, 0, stream>>>(q, Ks, Vt2, o);
  } else {
    dim3 grid((L_TOK + QBLK1 - 1) / QBLK1, NBH);
    var_attn<<<grid, 256, 0, stream>>>(q, k, v, o);
  }
}

// Round 10
// 38.863 us; speedup vs baseline: 1.1551x; 1.1551x over previous
//
#include <hip/hip_runtime.h>

// VAR flex-attention, MI355X gfx950. Mask == "q attends to keys [0, block_end(q))".
// R10: R7 structure (512-thread / 8-wave blocks, QBLK=128, 64-kv tiles, depth-3
// triple-buffered gload_lds, counted WAITV(4/2/0), fixed-max exp2 softmax,
// gathered pre-swizzled V, long-first XCD dispatch) with REGISTER-PRESSURE FIX:
// __launch_bounds__(512,6) (VGPR cap 85, was 8->64 = spilling) and a fused
// mask+exp2+sum+cvt_pk softmax pass (no s[16]/p[16] staging arrays; peak live
// regs ~70). Single-change round vs R7 for attribution.

typedef float  f32x4 __attribute__((ext_vector_type(4)));
typedef short  s16x8 __attribute__((ext_vector_type(8)));
typedef short  s16x4 __attribute__((ext_vector_type(4)));
typedef unsigned int u32;
typedef u32    u32x4 __attribute__((ext_vector_type(4)));

#define L_TOK 680
#define LPAD  704
#define DHEAD 64
#define NBH   128
#define NTILE 11
#define SCALE_LOG2 0.18033688011112042f   // (1/8) * log2(e)

#define WAITV(n) asm volatile("s_waitcnt vmcnt(" #n ")" ::: "memory")

__device__ __forceinline__ int kv_len(int q) {
  return q < 1 ? 1 : q < 5 ? 5 : q < 14 ? 14 : q < 30 ? 30 : q < 55 ? 55
       : q < 91 ? 91 : q < 155 ? 155 : q < 255 ? 255 : q < 424 ? 424 : L_TOK;
}

__device__ __forceinline__ short f2bf(float x) {
  unsigned u = __float_as_uint(x);
  return (short)((u + 0x7FFFu + ((u >> 16) & 1u)) >> 16);
}

__device__ __forceinline__ s16x8 cvt8(f32x4 a, f32x4 b, float sc) {
  s16x8 f;
  f[0] = f2bf(a[0] * sc); f[1] = f2bf(a[1] * sc);
  f[2] = f2bf(a[2] * sc); f[3] = f2bf(a[3] * sc);
  f[4] = f2bf(b[0] * sc); f[5] = f2bf(b[1] * sc);
  f[6] = f2bf(b[2] * sc); f[7] = f2bf(b[3] * sc);
  return f;
}

__device__ __forceinline__ float exp2f_raw(float x) {
  float r; asm("v_exp_f32 %0, %1" : "=v"(r) : "v"(x)); return r;
}
__device__ __forceinline__ u32 cvtpk(float lo, float hi) {
  u32 r; asm("v_cvt_pk_bf16_f32 %0, %1, %2" : "=v"(r) : "v"(lo), "v"(hi)); return r;
}

__device__ __forceinline__ void gload16(const void* g, void* l) {
  __builtin_amdgcn_global_load_lds(
      (const __attribute__((address_space(1))) u32*)g,
      (__attribute__((address_space(3))) u32*)l, 16, 0, 0);
}

// ---- fused prepass (identical to R4..R9, proven) ----------------------------
__global__ __launch_bounds__(256) void prep_kv(
    const float* __restrict__ Kg, const float* __restrict__ Vg,
    short* __restrict__ Ks, short* __restrict__ Vt2)
{
  int b = blockIdx.x, tid = threadIdx.x;
  if (b < 2816) {
    int g = b * 256 + tid;
    int bh = g / (LPAD * 8);
    int rem = g - bh * (LPAD * 8);
    int r = rem >> 3, c = rem & 7;
    s16x8 o = (s16x8)0;
    if (r < L_TOK) {
      const float* src = Kg + ((size_t)(bh * L_TOK + r)) * DHEAD + c * 8;
      f32x4 a = *(const f32x4*)src;
      f32x4 bb = *(const f32x4*)(src + 4);
      o = cvt8(a, bb, 1.0f);
    }
    int cp = c ^ (r & 7);
    *(s16x8*)(Ks + ((size_t)(bh * LPAD + r)) * DHEAD + cp * 8) = o;
  } else {
    int bid = b - 2816;                       // bh*11 + t
    int bh = bid / NTILE, t = bid - bh * NTILE;
    int lg = tid & 3, l15 = (tid >> 2) & 15, dt = tid >> 6;
    int d = dt * 16 + l15;
    const float* vsrc = Vg + (size_t)bh * L_TOK * DHEAD + d;
    short* rowbase = Vt2 + ((size_t)(bh * NTILE + t)) * 4096 + d * 64;
    #pragma unroll
    for (int f = 0; f < 2; ++f) {
      short u[8];
      #pragma unroll
      for (int i = 0; i < 4; ++i) {
        int kv = t * 64 + f * 32 + lg * 4 + i;
        u[i]     = (kv < L_TOK)      ? f2bf(vsrc[(size_t)kv * DHEAD])        : (short)0;
        u[4 + i] = (kv + 16 < L_TOK) ? f2bf(vsrc[(size_t)(kv + 16) * DHEAD]) : (short)0;
      }
      int pos = (2 * lg + f) ^ (l15 & 7);
      *(s16x8*)(rowbase + pos * 8) = *(const s16x8*)u;
    }
  }
}

// ---- main kernel: 8 waves x 16q = 128q per block, 64-kv tiles, depth-3 ------
__global__ __launch_bounds__(512, 6) void var_attn10(
    const float* __restrict__ Qg, const short* __restrict__ Ks,
    const short* __restrict__ Vt2, float* __restrict__ Og)
{
  const int tid  = threadIdx.x;
  const int lane = tid & 63, wave = tid >> 6;
  const int l15  = lane & 15, lg = lane >> 4;

  // dispatch: bid&7 -> XCD-stable bh-low (L2 reuse); long q-tiles first
  int bid  = blockIdx.x;                      // 0..767
  int bhlo = bid & 7;
  int t_   = bid >> 3;                        // 0..95
  int qbi  = t_ >> 4;                         // 0..5
  int bhhi = t_ & 15;
  int qb2  = (qbi < 3) ? (qbi + 3) : (5 - qbi);   // 3,4,5,2,1,0 (nt 11,11,11,7,4,3)
  int bh   = bhhi * 8 + bhlo;
  int qblk = qb2 * 128;

  __shared__ short kbuf[3][64 * DHEAD];       // 3 x 8KB
  __shared__ short vbuf[3][64 * DHEAD];       // 3 x 8KB (gathered V fragments)

  const int qw        = qblk + wave * 16;
  const int qc        = min(qw + l15, L_TOK - 1);
  const int my_kvlen  = kv_len(qc);
  const int kvmin_w   = kv_len(min(qw, L_TOK - 1));
  const int kv_need_w = (qw < L_TOK) ? kv_len(min(qw + 15, L_TOK - 1)) : 0;
  const int nkv       = kv_len(min(qblk + 127, L_TOK - 1));
  const int nt        = (nkv + 63) >> 6;      // 3,4,7,11,11,11 -> >= 3

  s16x8 qfrag[2];
  {
    const float* qp = Qg + ((size_t)(bh * L_TOK + qc)) * DHEAD + lg * 8;
    #pragma unroll
    for (int ks = 0; ks < 2; ++ks) {
      f32x4 a = *(const f32x4*)(qp + ks * 32);
      f32x4 b = *(const f32x4*)(qp + ks * 32 + 4);
      qfrag[ks] = cvt8(a, b, SCALE_LOG2);
    }
  }

  const short* ksb = Ks + (size_t)bh * LPAD * DHEAD;
  const short* vtb = Vt2 + (size_t)bh * NTILE * 4096;

  auto issue = [&](int kt, int buf) {         // one K + one V 16B load per lane
    const int off = tid * 16;
    gload16((const char*)(ksb + kt * 4096) + off, (char*)&kbuf[buf][0] + off);
    gload16((const char*)(vtb + (size_t)kt * 4096) + off, (char*)&vbuf[buf][0] + off);
  };

  issue(0, 0);
  issue(1, 1);
  issue(2, 2);

  // hoisted loop-invariant LDS byte offsets
  const int swz   = l15 & 7;
  const int koff0 = l15 * 128 + ((lg    ) ^ swz) * 16;
  const int koff1 = l15 * 128 + ((lg + 4) ^ swz) * 16;
  const int voff0 = l15 * 128 + ((2 * lg    ) ^ swz) * 16;
  const int voff1 = l15 * 128 + ((2 * lg + 1) ^ swz) * 16;

  f32x4 oacc[4] = {};
  float l_run = 0.0f;
  int cur = 0;                                // kt % 3

  for (int kt = 0; kt < nt; ++kt) {
    if (kt + 2 < nt)      { WAITV(4); }       // tiles kt+1, kt+2 in flight
    else if (kt + 1 < nt) { WAITV(2); }       // tile kt+1 in flight
    else                  { WAITV(0); }
    __builtin_amdgcn_s_barrier();

    const int kv0 = kt * 64;
    if (kv0 < kv_need_w) {
      const char* kb = (const char*)&kbuf[cur][0];
      const char* vb = (const char*)&vbuf[cur][0];

      // QK^T (swapped): sacc[t16] = S^T [16k x 16q], log2-domain scores
      f32x4 sacc[4] = {};
      __builtin_amdgcn_s_setprio(1);
      #pragma unroll
      for (int t16 = 0; t16 < 4; ++t16) {
        s16x8 kf0 = *(const s16x8*)(kb + t16 * 2048 + koff0);
        s16x8 kf1 = *(const s16x8*)(kb + t16 * 2048 + koff1);
        sacc[t16] = __builtin_amdgcn_mfma_f32_16x16x32_bf16(kf0, qfrag[0], sacc[t16], 0, 0, 0);
        sacc[t16] = __builtin_amdgcn_mfma_f32_16x16x32_bf16(kf1, qfrag[1], sacc[t16], 0, 0, 0);
      }
      __builtin_amdgcn_s_setprio(0);

      // fused mask + fixed-max exp2 + sum + cvt_pk (min live regs: each sacc
      // quad -> 4 exp2 -> 2 u32, then dead; no s[16]/p[16] staging arrays)
      u32x4 w0, w1;
      float lsum = 0.0f;
      if (kv0 + 64 <= kvmin_w) {              // wave-uniform full tile
        #pragma unroll
        for (int t16 = 0; t16 < 4; ++t16) {
          float a = exp2f_raw(sacc[t16][0]);
          float b = exp2f_raw(sacc[t16][1]);
          float c = exp2f_raw(sacc[t16][2]);
          float d = exp2f_raw(sacc[t16][3]);
          lsum += (a + b) + (c + d);
          u32 lo = cvtpk(a, b), hi = cvtpk(c, d);
          if (t16 < 2) { w0[2 * t16] = lo; w0[2 * t16 + 1] = hi; }
          else         { w1[2 * (t16 - 2)] = lo; w1[2 * (t16 - 2) + 1] = hi; }
        }
      } else {
        const int kbase = kv0 + lg * 4;
        #pragma unroll
        for (int t16 = 0; t16 < 4; ++t16) {
          float a = (kbase + t16 * 16     < my_kvlen) ? exp2f_raw(sacc[t16][0]) : 0.0f;
          float b = (kbase + t16 * 16 + 1 < my_kvlen) ? exp2f_raw(sacc[t16][1]) : 0.0f;
          float c = (kbase + t16 * 16 + 2 < my_kvlen) ? exp2f_raw(sacc[t16][2]) : 0.0f;
          float d = (kbase + t16 * 16 + 3 < my_kvlen) ? exp2f_raw(sacc[t16][3]) : 0.0f;
          lsum += (a + b) + (c + d);
          u32 lo = cvtpk(a, b), hi = cvtpk(c, d);
          if (t16 < 2) { w0[2 * t16] = lo; w0[2 * t16 + 1] = hi; }
          else         { w1[2 * (t16 - 2)] = lo; w1[2 * (t16 - 2) + 1] = hi; }
        }
      }
      l_run += lsum;
      s16x8 pf0 = __builtin_bit_cast(s16x8, w0);
      s16x8 pf1 = __builtin_bit_cast(s16x8, w1);

      // PV: gathered V fragments, straight b128 reads (pre-swizzled)
      __builtin_amdgcn_s_setprio(1);
      #pragma unroll
      for (int dt = 0; dt < 4; ++dt) {
        s16x8 vf0 = *(const s16x8*)(vb + dt * 2048 + voff0);
        s16x8 vf1 = *(const s16x8*)(vb + dt * 2048 + voff1);
        oacc[dt] = __builtin_amdgcn_mfma_f32_16x16x32_bf16(pf0, vf0, oacc[dt], 0, 0, 0);
        oacc[dt] = __builtin_amdgcn_mfma_f32_16x16x32_bf16(pf1, vf1, oacc[dt], 0, 0, 0);
      }
      __builtin_amdgcn_s_setprio(0);
    }
    __builtin_amdgcn_s_barrier();
    if (kt + 3 < nt) issue(kt + 3, cur);      // (kt+3)%3 == cur, just consumed
    cur = (cur == 2) ? 0 : cur + 1;
  }

  // epilogue: reduce l across the 4 replica lane-groups, normalize, store
  l_run += __shfl_xor(l_run, 16);
  l_run += __shfl_xor(l_run, 32);
  float linv = 1.0f / l_run;
  float li_q[4];
  #pragma unroll
  for (int r = 0; r < 4; ++r) li_q[r] = __shfl(linv, lg * 4 + r);
  #pragma unroll
  for (int r = 0; r < 4; ++r) {
    int qo = qw + lg * 4 + r;
    if (qo < L_TOK) {
      float* dst = Og + ((size_t)(bh * L_TOK + qo)) * DHEAD + l15;
      #pragma unroll
      for (int dt = 0; dt < 4; ++dt) dst[dt * 16] = oacc[dt][r] * li_q[r];
    }
  }
}

// ---------------- R1 fallback kernel (f32 direct, no workspace) --------------
#define QBLK1  64
#define KVBLK1 32
#define VTS    36
__global__ __launch_bounds__(256, 2) void var_attn(
    const float* __restrict__ Qg, const float* __restrict__ Kg,
    const float* __restrict__ Vg, float* __restrict__ Og)
{
  const int tid  = threadIdx.x;
  const int bh   = blockIdx.y;
  const int qblk = blockIdx.x * QBLK1;
  const int wave = tid >> 6;
  const int lane = tid & 63;
  const int l15  = lane & 15;
  const int lg   = lane >> 4;

  __shared__ short kbuf[KVBLK1 * DHEAD];
  __shared__ short vtbuf[DHEAD * VTS];

  const int qw   = qblk + wave * 16;
  const int qc   = min(qw + l15, L_TOK - 1);
  const int my_kvlen  = kv_len(qc);
  const int kv_need_w = kv_len(min(qw + 15, L_TOK - 1));
  const int nkv       = kv_len(min(qblk + QBLK1 - 1, L_TOK - 1));

  s16x8 qfrag[2];
  {
    const float* qptr = Qg + ((size_t)(bh * L_TOK + qc)) * DHEAD + lg * 8;
    #pragma unroll
    for (int ks = 0; ks < 2; ++ks) {
      f32x4 a = *(const f32x4*)(qptr + ks * 32);
      f32x4 b = *(const f32x4*)(qptr + ks * 32 + 4);
      qfrag[ks] = cvt8(a, b, 0.125f);
    }
  }

  f32x4 oacc[4] = {};
  float m_run = -1e30f, l_run = 0.0f;

  const int stage_r = tid >> 3;
  const int stage_c = (tid & 7) * 8;
  const float* kbase = Kg + (size_t)bh * L_TOK * DHEAD;
  const float* vbase = Vg + (size_t)bh * L_TOK * DHEAD;

  for (int kv0 = 0; kv0 < nkv; kv0 += KVBLK1) {
    {
      const int rsrc = min(kv0 + stage_r, L_TOK - 1);
      const float* ks_ = kbase + (size_t)rsrc * DHEAD + stage_c;
      f32x4 a = *(const f32x4*)ks_;
      f32x4 b = *(const f32x4*)(ks_ + 4);
      s16x8 kf = cvt8(a, b, 1.0f);
      int boff = (stage_r * 128 + stage_c * 2) ^ ((stage_r & 7) << 4);
      *(s16x8*)((char*)kbuf + boff) = kf;
      const float* vs_ = vbase + (size_t)rsrc * DHEAD + stage_c;
      f32x4 c = *(const f32x4*)vs_;
      f32x4 d = *(const f32x4*)(vs_ + 4);
      #pragma unroll
      for (int i = 0; i < 4; ++i) vtbuf[(stage_c + i) * VTS + stage_r] = f2bf(c[i]);
      #pragma unroll
      for (int i = 0; i < 4; ++i) vtbuf[(stage_c + 4 + i) * VTS + stage_r] = f2bf(d[i]);
    }
    __syncthreads();
    if (kv0 < kv_need_w) {
      f32x4 sacc[2] = {};
      #pragma unroll
      for (int t = 0; t < 2; ++t) {
        const int kr = t * 16 + l15;
        #pragma unroll
        for (int ks = 0; ks < 2; ++ks) {
          int boff = (kr * 128 + (lg * 8 + ks * 32) * 2) ^ ((kr & 7) << 4);
          s16x8 kf = *(const s16x8*)((char*)kbuf + boff);
          sacc[t] = __builtin_amdgcn_mfma_f32_16x16x32_bf16(kf, qfrag[ks], sacc[t], 0, 0, 0);
        }
      }
      float s[8];
      #pragma unroll
      for (int t = 0; t < 2; ++t)
        #pragma unroll
        for (int r = 0; r < 4; ++r) {
          int key = kv0 + t * 16 + lg * 4 + r;
          s[t * 4 + r] = (key < my_kvlen) ? sacc[t][r] : -1e30f;
        }
      float mt = s[0];
      #pragma unroll
      for (int i = 1; i < 8; ++i) mt = fmaxf(mt, s[i]);
      mt = fmaxf(mt, __shfl_xor(mt, 16));
      mt = fmaxf(mt, __shfl_xor(mt, 32));
      float m_new = fmaxf(m_run, mt);
      float sc = __expf(m_run - m_new);
      float psum = 0.0f;
      short pf[8];
      #pragma unroll
      for (int i = 0; i < 8; ++i) {
        float pp = __expf(s[i] - m_new);
        psum += pp;
        pf[i] = f2bf(pp);
      }
      psum += __shfl_xor(psum, 16);
      psum += __shfl_xor(psum, 32);
      l_run = l_run * sc + psum;
      m_run = m_new;
      float sc_q[4];
      #pragma unroll
      for (int r = 0; r < 4; ++r) sc_q[r] = __shfl(sc, lg * 4 + r);
      #pragma unroll
      for (int dt = 0; dt < 4; ++dt)
        #pragma unroll
        for (int r = 0; r < 4; ++r) oacc[dt][r] *= sc_q[r];
      s16x8 pfrag;
      #pragma unroll
      for (int i = 0; i < 8; ++i) pfrag[i] = pf[i];
      #pragma unroll
      for (int dt = 0; dt < 4; ++dt) {
        const short* row = vtbuf + (dt * 16 + l15) * VTS + lg * 4;
        s16x4 v0 = *(const s16x4*)row;
        s16x4 v1 = *(const s16x4*)(row + 16);
        s16x8 vf;
        vf[0] = v0[0]; vf[1] = v0[1]; vf[2] = v0[2]; vf[3] = v0[3];
        vf[4] = v1[0]; vf[5] = v1[1]; vf[6] = v1[2]; vf[7] = v1[3];
        oacc[dt] = __builtin_amdgcn_mfma_f32_16x16x32_bf16(pfrag, vf, oacc[dt], 0, 0, 0);
      }
    }
    __syncthreads();
  }

  float linv = 1.0f / l_run;
  float li_q[4];
  #pragma unroll
  for (int r = 0; r < 4; ++r) li_q[r] = __shfl(linv, lg * 4 + r);
  #pragma unroll
  for (int r = 0; r < 4; ++r) {
    int qo = qw + lg * 4 + r;
    if (qo < L_TOK) {
      float* dst = Og + ((size_t)(bh * L_TOK + qo)) * DHEAD + l15;
      #pragma unroll
      for (int dt = 0; dt < 4; ++dt) dst[dt * 16] = oacc[dt][r] * li_q[r];
    }
  }
}

extern "C" void kernel_launch(void* const* d_in, const int* in_sizes, int n_in,
                              void* d_out, int out_size, void* d_ws, size_t ws_size,
                              hipStream_t stream) {
  const float* q = (const float*)d_in[0];
  const float* k = (const float*)d_in[1];
  const float* v = (const float*)d_in[2];
  float* o = (float*)d_out;

  const size_t ksz  = (size_t)NBH * LPAD * DHEAD;     // shorts (= Vt2 size too)
  const size_t need = 2 * ksz * sizeof(short);        // 23.1 MB
  if (ws_size >= need) {
    short* Ks  = (short*)d_ws;
    short* Vt2 = Ks + ksz;
    prep_kv<<<4224, 256, 0, stream>>>(k, v, Ks, Vt2);
    var_attn10<<<768, 512, 0, stream>>>(q, Ks, Vt2, o);
  } else {
    dim3 grid((L_TOK + QBLK1 - 1) / QBLK1, NBH);
    var_attn<<<grid, 256, 0, stream>>>(q, k, v, o);
  }
}